// Round 1
// baseline (495.064 us; speedup 1.0000x reference)
//
#include <hip/hip_runtime.h>

// ---------------- problem constants ----------------
constexpr int BATCH = 4;
constexpr int HS    = 64;     // H
constexpr int WSZ   = 64;     // W
constexpr int LSEQ  = 4096;   // L = H*W
constexpr int DM    = 96;     // d_model
constexpr int DI    = 192;    // d_inner
constexpr int NS    = 16;     // d_state
constexpr int RK    = 6;      // dt_rank
constexpr int KD    = 4;      // scan directions
constexpr int XPC   = 38;     // dt_rank + 2*d_state
constexpr int NCH   = 64;     // chunks along L
constexpr int CLEN  = 64;     // chunk length

// scan index l -> spatial position p (row-major h*64+w), per direction
__device__ __forceinline__ int pos_of(int k, int l) {
  switch (k & 3) {
    case 0: return l;
    case 1: return ((l & 63) << 6) | (l >> 6);          // l = w*H+h -> p = h*W+w
    case 2: return LSEQ - 1 - l;
    default: { int lp = LSEQ - 1 - l; return ((lp & 63) << 6) | (lp >> 6); }
  }
}

// ---------------- generic small-K GEMM: C[M,NN] = A[M,KK] * Bw[NN,KK]^T ----------------
template <int NN, int KK, int TM>
__launch_bounds__(256)
__global__ void gemm_rt(const float* __restrict__ A, const float* __restrict__ Bw,
                        float* __restrict__ C, int M) {
  constexpr int TN  = 64;
  constexpr int RPT = TM / 16;          // rows per thread
  constexpr int SA  = TM + 2;           // padded stride
  constexpr int KQ  = KK / 4;
  __shared__ float AsT[KK][SA];
  __shared__ float BsT[KK][TN];
  const int t = threadIdx.x;
  const int row0 = blockIdx.y * TM;
  const int col0 = blockIdx.x * TN;

  for (int idx = t; idx < TM * KQ; idx += 256) {
    int r = idx / KQ, kq = idx % KQ;
    float4 v = *(const float4*)&A[(size_t)(row0 + r) * KK + kq * 4];
    AsT[kq*4+0][r] = v.x; AsT[kq*4+1][r] = v.y;
    AsT[kq*4+2][r] = v.z; AsT[kq*4+3][r] = v.w;
  }
  for (int idx = t; idx < TN * KQ; idx += 256) {
    int c = idx / KQ, kq = idx % KQ;
    int col = col0 + c;
    float4 v = make_float4(0.f, 0.f, 0.f, 0.f);
    if (col < NN) v = *(const float4*)&Bw[(size_t)col * KK + kq * 4];
    BsT[kq*4+0][c] = v.x; BsT[kq*4+1][c] = v.y;
    BsT[kq*4+2][c] = v.z; BsT[kq*4+3][c] = v.w;
  }
  __syncthreads();

  const int tc = t & 15;        // 16 col groups * 4 cols
  const int tr = t >> 4;        // 16 row groups * RPT rows
  float acc[RPT][4];
  #pragma unroll
  for (int i = 0; i < RPT; ++i)
    { acc[i][0]=0.f; acc[i][1]=0.f; acc[i][2]=0.f; acc[i][3]=0.f; }

  for (int kk = 0; kk < KK; ++kk) {
    float4 bv = *(const float4*)&BsT[kk][tc * 4];
    #pragma unroll
    for (int i = 0; i < RPT; ++i) {
      float a = AsT[kk][tr * RPT + i];
      acc[i][0] += a * bv.x; acc[i][1] += a * bv.y;
      acc[i][2] += a * bv.z; acc[i][3] += a * bv.w;
    }
  }
  int c = col0 + tc * 4;
  if (c < NN) {
    #pragma unroll
    for (int i = 0; i < RPT; ++i) {
      size_t r0 = (size_t)(row0 + tr * RPT + i) * NN + c;
      *(float4*)&C[r0] = make_float4(acc[i][0], acc[i][1], acc[i][2], acc[i][3]);
    }
  }
}

// ---------------- depthwise 3x3 conv + bias + SiLU ----------------
__launch_bounds__(256)
__global__ void conv_silu(const float* __restrict__ xz, const float* __restrict__ cw,
                          const float* __restrict__ cb, float* __restrict__ xc) {
  int idx = blockIdx.x * 256 + threadIdx.x;     // over B*L*DI, grid exact
  int d = idx % DI;
  int p = (idx / DI) % LSEQ;
  int b = idx / (DI * LSEQ);
  int h = p >> 6, w = p & 63;
  float acc = cb[d];
  #pragma unroll
  for (int kh = 0; kh < 3; ++kh) {
    int hh = h + kh - 1;
    if ((unsigned)hh >= (unsigned)HS) continue;
    #pragma unroll
    for (int kw = 0; kw < 3; ++kw) {
      int ww = w + kw - 1;
      if ((unsigned)ww >= (unsigned)WSZ) continue;
      acc += xz[((size_t)b * LSEQ + (hh << 6) + ww) * (2 * DI) + d] * cw[d * 9 + kh * 3 + kw];
    }
  }
  xc[idx] = acc / (1.f + __expf(-acc));   // SiLU
}

// ---------------- x_proj (38x192 dots) + dt proj + softplus -> delta, Bs, Cs ----------------
constexpr int LT = 16;   // l positions per block
__launch_bounds__(256)
__global__ void xproj(const float* __restrict__ xc, const float* __restrict__ xw,
                      const float* __restrict__ dtw, const float* __restrict__ dtb,
                      float* __restrict__ delta, float* __restrict__ Bsb,
                      float* __restrict__ Csb) {
  __shared__ float wx[40][196];
  __shared__ float xt[LT][196];
  __shared__ float xdbl[LT][40];
  __shared__ float dtw_s[DI * RK];
  __shared__ float dtb_s[DI];
  const int t = threadIdx.x;
  const int k = blockIdx.y, b = blockIdx.z;
  const int l0 = blockIdx.x * LT;

  for (int idx = t; idx < XPC * 48; idx += 256) {
    int c = idx / 48, q = idx % 48;
    *(float4*)&wx[c][q * 4] = *(const float4*)&xw[((size_t)k * XPC + c) * DI + q * 4];
  }
  for (int idx = t; idx < 2 * 48; idx += 256) {
    int c = XPC + idx / 48, q = idx % 48;
    *(float4*)&wx[c][q * 4] = make_float4(0.f, 0.f, 0.f, 0.f);
  }
  for (int idx = t; idx < LT * 48; idx += 256) {
    int li = idx / 48, q = idx % 48;
    int p = pos_of(k, l0 + li);
    *(float4*)&xt[li][q * 4] = *(const float4*)&xc[((size_t)b * LSEQ + p) * DI + q * 4];
  }
  for (int idx = t; idx < DI * RK; idx += 256) dtw_s[idx] = dtw[(size_t)k * DI * RK + idx];
  for (int idx = t; idx < DI; idx += 256)      dtb_s[idx] = dtb[k * DI + idx];
  __syncthreads();

  // 16 li x 20 col-pairs = 320 dot-units (each 2 dots of length 192)
  for (int idx = t; idx < LT * 20; idx += 256) {
    int li = idx & 15, cg = idx >> 4;
    float a0 = 0.f, a1 = 0.f;
    for (int q = 0; q < 48; ++q) {
      float4 xv = *(const float4*)&xt[li][q * 4];
      float4 w0 = *(const float4*)&wx[cg * 2][q * 4];
      float4 w1 = *(const float4*)&wx[cg * 2 + 1][q * 4];
      a0 += xv.x * w0.x + xv.y * w0.y + xv.z * w0.z + xv.w * w0.w;
      a1 += xv.x * w1.x + xv.y * w1.y + xv.z * w1.z + xv.w * w1.w;
    }
    xdbl[li][cg * 2] = a0; xdbl[li][cg * 2 + 1] = a1;
  }
  __syncthreads();

  // delta = softplus(dt_b + dt_w @ x_dbl[0:6])
  for (int idx = t; idx < LT * DI; idx += 256) {
    int li = idx / DI, d = idx % DI;
    float s = dtb_s[d];
    #pragma unroll
    for (int r = 0; r < RK; ++r) s += xdbl[li][r] * dtw_s[d * RK + r];
    float dv = (s > 20.f) ? s : log1pf(__expf(s));
    delta[(((size_t)(b * KD + k)) * LSEQ + l0 + li) * DI + d] = dv;
  }
  // Bs = x_dbl[6:22], Cs = x_dbl[22:38]
  for (int idx = t; idx < LT * 32; idx += 256) {
    int li = idx / 32, j = idx % 32;
    float v = xdbl[li][RK + j];
    size_t base = (((size_t)(b * KD + k)) * LSEQ + l0 + li) * NS;
    if (j < NS) Bsb[base + j] = v; else Csb[base + (j - NS)] = v;
  }
}

// ---------------- scan phase 1: per-chunk local states + sum(delta) ----------------
__launch_bounds__(192)
__global__ void scan_phase1(const float* __restrict__ delta, const float* __restrict__ xc,
                            const float* __restrict__ Bsb, const float* __restrict__ Alog,
                            float* __restrict__ hN, float* __restrict__ sumdB) {
  const int d = threadIdx.x;
  const int ch = blockIdx.x, k = blockIdx.y, b = blockIdx.z;
  const int bk = b * KD + k;
  float An[NS];
  {
    const float4* Ap = (const float4*)&Alog[((size_t)k * DI + d) * NS];
    #pragma unroll
    for (int q = 0; q < 4; ++q) {
      float4 a = Ap[q];
      An[q*4+0] = -__expf(a.x); An[q*4+1] = -__expf(a.y);
      An[q*4+2] = -__expf(a.z); An[q*4+3] = -__expf(a.w);
    }
  }
  float h[NS];
  #pragma unroll
  for (int n = 0; n < NS; ++n) h[n] = 0.f;
  float sumd = 0.f;
  const int l0 = ch * CLEN;
  for (int j = 0; j < CLEN; ++j) {
    const int l = l0 + j;
    const size_t base = (size_t)bk * LSEQ + l;
    float dl = delta[base * DI + d];
    int p = pos_of(k, l);
    float u = xc[((size_t)b * LSEQ + p) * DI + d];
    float du = dl * u;
    const float4* Bp = (const float4*)&Bsb[base * NS];
    float Bv[NS];
    #pragma unroll
    for (int q = 0; q < 4; ++q) {
      float4 v = Bp[q];
      Bv[q*4+0] = v.x; Bv[q*4+1] = v.y; Bv[q*4+2] = v.z; Bv[q*4+3] = v.w;
    }
    #pragma unroll
    for (int n = 0; n < NS; ++n)
      h[n] = __expf(dl * An[n]) * h[n] + du * Bv[n];
    sumd += dl;
  }
  const size_t o = ((size_t)bk * NCH + ch) * DI + d;
  float4* Hp = (float4*)&hN[o * NS];
  #pragma unroll
  for (int q = 0; q < 4; ++q)
    Hp[q] = make_float4(h[q*4+0], h[q*4+1], h[q*4+2], h[q*4+3]);
  sumdB[o] = sumd;
}

// ---------------- sequential chunk combine: entry state per chunk ----------------
__launch_bounds__(256)
__global__ void chunk_combine(const float* __restrict__ hN, const float* __restrict__ sumdB,
                              const float* __restrict__ Alog, float* __restrict__ hin) {
  const int tid = blockIdx.x * 256 + threadIdx.x;   // over B*K*D*N
  const int n  = tid & 15;
  const int dd = tid >> 4;
  const int d  = dd % DI;
  const int bk = dd / DI;
  const int k  = bk & 3;
  const float An = -__expf(Alog[((size_t)k * DI + d) * NS + n]);
  float h = 0.f;
  for (int c = 0; c < NCH; ++c) {
    const size_t o = ((size_t)bk * NCH + c) * DI + d;
    hin[o * NS + n] = h;
    h = hN[o * NS + n] + __expf(An * sumdB[o]) * h;
  }
}

// ---------------- scan phase 2: recompute with entry state, emit y (merged) ----------------
__launch_bounds__(192)
__global__ void scan_phase2(const float* __restrict__ delta, const float* __restrict__ xc,
                            const float* __restrict__ Bsb, const float* __restrict__ Csb,
                            const float* __restrict__ Alog, const float* __restrict__ hin,
                            float* __restrict__ yg) {
  const int d = threadIdx.x;
  const int ch = blockIdx.x, k = blockIdx.y, b = blockIdx.z;
  const int bk = b * KD + k;
  float An[NS];
  {
    const float4* Ap = (const float4*)&Alog[((size_t)k * DI + d) * NS];
    #pragma unroll
    for (int q = 0; q < 4; ++q) {
      float4 a = Ap[q];
      An[q*4+0] = -__expf(a.x); An[q*4+1] = -__expf(a.y);
      An[q*4+2] = -__expf(a.z); An[q*4+3] = -__expf(a.w);
    }
  }
  float h[NS];
  {
    const size_t o = ((size_t)bk * NCH + ch) * DI + d;
    const float4* Hp = (const float4*)&hin[o * NS];
    #pragma unroll
    for (int q = 0; q < 4; ++q) {
      float4 v = Hp[q];
      h[q*4+0] = v.x; h[q*4+1] = v.y; h[q*4+2] = v.z; h[q*4+3] = v.w;
    }
  }
  const int l0 = ch * CLEN;
  for (int j = 0; j < CLEN; ++j) {
    const int l = l0 + j;
    const size_t base = (size_t)bk * LSEQ + l;
    float dl = delta[base * DI + d];
    int p = pos_of(k, l);
    float u = xc[((size_t)b * LSEQ + p) * DI + d];
    float du = dl * u;
    const float4* Bp = (const float4*)&Bsb[base * NS];
    const float4* Cp = (const float4*)&Csb[base * NS];
    float Bv[NS], Cv[NS];
    #pragma unroll
    for (int q = 0; q < 4; ++q) {
      float4 v = Bp[q];
      Bv[q*4+0] = v.x; Bv[q*4+1] = v.y; Bv[q*4+2] = v.z; Bv[q*4+3] = v.w;
      float4 c4 = Cp[q];
      Cv[q*4+0] = c4.x; Cv[q*4+1] = c4.y; Cv[q*4+2] = c4.z; Cv[q*4+3] = c4.w;
    }
    float y = 0.f;
    #pragma unroll
    for (int n = 0; n < NS; ++n) {
      h[n] = __expf(dl * An[n]) * h[n] + du * Bv[n];
      y += h[n] * Cv[n];
    }
    atomicAdd(&yg[((size_t)b * LSEQ + p) * DI + d], y);
  }
}

// ---------------- direction merge (Ds term) + LayerNorm + SiLU gate ----------------
__launch_bounds__(192)
__global__ void fuse_ln(const float* __restrict__ yg, const float* __restrict__ xc,
                        const float* __restrict__ Ds, const float* __restrict__ xz,
                        const float* __restrict__ lnw, const float* __restrict__ lnb,
                        float* __restrict__ ymul) {
  const int row = blockIdx.x;        // b*L + p
  const int d = threadIdx.x;
  float u = xc[(size_t)row * DI + d];
  float sDs = Ds[d] + Ds[DI + d] + Ds[2 * DI + d] + Ds[3 * DI + d];
  float y = yg[(size_t)row * DI + d] + sDs * u;
  float s1 = y, s2 = y * y;
  #pragma unroll
  for (int off = 32; off; off >>= 1) {
    s1 += __shfl_xor(s1, off);
    s2 += __shfl_xor(s2, off);
  }
  __shared__ float r1[3], r2[3];
  int wid = d >> 6;
  if ((d & 63) == 0) { r1[wid] = s1; r2[wid] = s2; }
  __syncthreads();
  float S1 = r1[0] + r1[1] + r1[2];
  float S2 = r2[0] + r2[1] + r2[2];
  float mu = S1 * (1.f / DI);
  float var = S2 * (1.f / DI) - mu * mu;
  float yn = (y - mu) * rsqrtf(var + 1e-5f) * lnw[d] + lnb[d];
  float zv = xz[(size_t)row * (2 * DI) + DI + d];
  float g = zv / (1.f + __expf(-zv));
  ymul[(size_t)row * DI + d] = yn * g;
}

// ---------------- launcher ----------------
extern "C" void kernel_launch(void* const* d_in, const int* in_sizes, int n_in,
                              void* d_out, int out_size, void* d_ws, size_t ws_size,
                              hipStream_t stream) {
  (void)in_sizes; (void)n_in; (void)out_size; (void)ws_size;
  const float* x          = (const float*)d_in[0];
  const float* in_proj_w  = (const float*)d_in[1];
  const float* conv_w     = (const float*)d_in[2];
  const float* conv_b     = (const float*)d_in[3];
  const float* x_proj_w   = (const float*)d_in[4];
  const float* dt_w       = (const float*)d_in[5];
  const float* dt_b       = (const float*)d_in[6];
  const float* A_logs     = (const float*)d_in[7];
  const float* Ds         = (const float*)d_in[8];
  const float* ln_w       = (const float*)d_in[9];
  const float* ln_b       = (const float*)d_in[10];
  const float* out_proj_w = (const float*)d_in[11];
  float* out = (float*)d_out;
  float* ws  = (float*)d_ws;

  constexpr size_t SZ_XZ    = (size_t)BATCH * LSEQ * 2 * DI;   // 6,291,456
  constexpr size_t SZ_XC    = (size_t)BATCH * LSEQ * DI;       // 3,145,728
  constexpr size_t SZ_DELTA = (size_t)BATCH * KD * LSEQ * DI;  // 12,582,912
  constexpr size_t SZ_BC    = (size_t)BATCH * KD * LSEQ * NS;  // 1,048,576
  constexpr size_t SZ_HN    = (size_t)BATCH * KD * NCH * DI * NS;
  constexpr size_t SZ_SUMD  = (size_t)BATCH * KD * NCH * DI;

  float* xz    = ws;
  float* xc    = xz + SZ_XZ;
  float* delta = xc + SZ_XC;
  float* Bsb   = delta + SZ_DELTA;
  float* Csb   = Bsb + SZ_BC;
  float* hN    = Csb + SZ_BC;
  float* sumd  = hN + SZ_HN;
  float* hin   = sumd + SZ_SUMD;
  float* yg    = hin + SZ_HN;
  float* ymul  = delta;   // delta dead after scan_phase2

  const int M = BATCH * LSEQ;  // 16384

  // 1. in_proj: xz[M,384] = x[M,96] @ in_proj_w[384,96]^T
  gemm_rt<2 * DI, DM, 32><<<dim3(6, M / 32), 256, 0, stream>>>(x, in_proj_w, xz, M);
  // 2. depthwise conv + SiLU -> xc (B,L,D)
  conv_silu<<<(BATCH * LSEQ * DI) / 256, 256, 0, stream>>>(xz, conv_w, conv_b, xc);
  // 3. x_proj + dt proj -> delta, Bs, Cs
  xproj<<<dim3(LSEQ / LT, KD, BATCH), 256, 0, stream>>>(xc, x_proj_w, dt_w, dt_b,
                                                        delta, Bsb, Csb);
  // 4. scan phase 1
  scan_phase1<<<dim3(NCH, KD, BATCH), 192, 0, stream>>>(delta, xc, Bsb, A_logs, hN, sumd);
  // 5. chunk combine
  chunk_combine<<<(BATCH * KD * DI * NS) / 256, 256, 0, stream>>>(hN, sumd, A_logs, hin);
  // 6. scan phase 2 -> yg (merged over directions)
  hipMemsetAsync(yg, 0, SZ_XC * sizeof(float), stream);
  scan_phase2<<<dim3(NCH, KD, BATCH), 192, 0, stream>>>(delta, xc, Bsb, Csb, A_logs, hin, yg);
  // 7. merge + LN + gate -> ymul (reuses delta buffer)
  fuse_ln<<<M, DI, 0, stream>>>(yg, xc, Ds, xz, ln_w, ln_b, ymul);
  // 8. out_proj: out[M,96] = ymul[M,192] @ out_proj_w[96,192]^T
  gemm_rt<DM, DI, 16><<<dim3(2, M / 16), 256, 0, stream>>>(ymul, out_proj_w, out, M);
}